// Round 7
// baseline (290.576 us; speedup 1.0000x reference)
//
#include <hip/hip_runtime.h>

// Problem constants (match reference)
#define DHW   (128*128*128)        // 2^21
#define CDHW  (4*DHW)              // 2^23
#define NTOT  (2*CDHW)             // 2^24 = 16,777,216
#define NACC  1024                 // one accumulator slot per block

// erode2 tiling: full x-row (32 f4), 8 owned y-rows, 16 owned z-planes.
// Primary thread assignment: fixed (row,col) so z-neighbors live in registers.
#define ROW4    32
#define IN_ROWS 12                 // input rows: 8 owned + 2*2 y-halo
#define S1_ROWS 10                 // s1 rows: 8 owned + 2*1
#define IN_P4   (IN_ROWS*ROW4)     // 384 f4 / input plane
#define S1_P4   (S1_ROWS*ROW4)     // 320 f4 / s1 plane
#define SLOT(z) (((z)+6)%3)

// TWO fused erosion steps; z-marching rolling planes; register z-chains for
// input and s1 center columns; PASS1 additionally fuses softmax+one-hot+square
// into the prefetch/commit path (reads raw input + targets).
template<int PASS1>
__global__ __launch_bounds__(256, 4) void erode2_kernel(
    const float4* __restrict__ src,      // pass>=2: op buffer
    const float4* __restrict__ rawin,    // pass1: raw logits (B,C,D,H,W)
    const int4*   __restrict__ tgt4,     // pass1: targets (B,D,H,W) int32
    float4* __restrict__ dst,
    const float* __restrict__ kern, const float* __restrict__ bias,
    const float* __restrict__ weight, float c1, float c2,
    int store, double* __restrict__ accs)
{
    __shared__ float4 lin[3 * IN_P4];   // 18.4 KB
    __shared__ float4 ls1[3 * S1_P4];   // 15.4 KB
    __shared__ double wsum[4];

    const int tid = threadIdx.x;
    const int bid = blockIdx.x;
    const int y0 = (bid & 15) << 3;
    const int zb = ((bid >> 4) & 7) << 4;
    const int bc = bid >> 7;            // b*4 + c in [0,8)
    const int b  = bc >> 2;
    const int cc = bc & 3;

    const float wk = kern[13];          // all 7 taps equal
    const float bs = bias[cc];

    const int col  = tid & 31;
    const int trow = tid >> 5;          // 0..7

    // primary: input row trow+2 <-> gy = y0+trow (always valid in y)
    const int goff0 = (y0 + trow) * 32 + col;      // global f4 offset in plane
    // ragged input rows {0,1,10,11} (tid<128; wave-uniform branch)
    const bool act1 = (tid < 128);
    const int  rr   = (tid < 32) ? 0 : (tid < 64) ? 1 : (tid < 96) ? 10 : 11;
    const int  gy1  = y0 + rr - 2;
    const bool lv1  = act1 && ((unsigned)gy1 < 128u);
    const int  loff1 = rr * 32 + col;
    const int  goff1 = (((unsigned)gy1 < 128u) ? gy1 : 0) * 32 + col;

    // ragged s1 rows {0,9} (tid<64; wave-uniform)
    const bool  sact1 = (tid < 64);
    const int   sr  = (tid < 32) ? 0 : 9;
    const float m1  = ((unsigned)(y0 + sr - 1) < 128u) ? 1.f : 0.f;
    const int   ci1 = (sr + 1) * 32 + col;
    const int   so1 = sr * 32 + col;

    const float lmask = (col == 0)  ? 0.f : 1.f;   // x=0 edge
    const float rmask = (col == 31) ? 0.f : 1.f;   // x=127 edge

    const float4 f4z = make_float4(0.f, 0.f, 0.f, 0.f);

    const float4* sp  = src + ((size_t)bc << 19);       // op slab (f4)
    float4*       dp  = dst + ((size_t)bc << 19);
    const float4* inb = rawin + ((size_t)b << 21);      // raw b-slab (f4)
    const int4*   tgb = tgt4 + ((size_t)b << 19);       // target b-slab (int4)

    // prefetch registers
    float4 pf0 = f4z, pf1 = f4z;                             // plain path
    float4 pA0 = f4z, pA1 = f4z, pA2 = f4z, pA3 = f4z;       // pass1 primary
    float4 pB0 = f4z, pB1 = f4z, pB2 = f4z, pB3 = f4z;       // pass1 ragged
    int4   pT0 = make_int4(-1, -1, -1, -1), pT1 = pT0;
    float  pm0 = 0.f, pm1 = 0.f;

    // register z-chains
    float4 i_m = f4z, i_c = f4z, i_p = f4z;    // input at z-1,z,z+1 (own col)
    float4 s_m = f4z, s_c = f4z, s_p = f4z;    // s1 at z-1,z,z+1 (own col)

    auto prefetch = [&](int L) {
        const bool zok = ((unsigned)L < 128u);
        if (PASS1) {
            pm0 = zok ? 1.f : 0.f;
            pm1 = (zok && lv1) ? 1.f : 0.f;
            pA0 = pA1 = pA2 = pA3 = f4z;
            pB0 = pB1 = pB2 = pB3 = f4z;
            if (zok) {
                const float4* zp = inb + ((size_t)L << 12) + goff0;
                pA0 = zp[0];
                pA1 = zp[1 << 19];
                pA2 = zp[2 << 19];
                pA3 = zp[3 << 19];
                pT0 = tgb[((size_t)L << 12) + goff0];
                if (lv1) {
                    const float4* zq = inb + ((size_t)L << 12) + goff1;
                    pB0 = zq[0];
                    pB1 = zq[1 << 19];
                    pB2 = zq[2 << 19];
                    pB3 = zq[3 << 19];
                    pT1 = tgb[((size_t)L << 12) + goff1];
                }
            }
        } else {
            pf0 = f4z; pf1 = f4z;
            if (zok) {
                const float4* zp = sp + ((size_t)L << 12);
                pf0 = zp[goff0];
                if (lv1) pf1 = zp[goff1];
            }
        }
    };

    // softmax residual squared for class cc (mask mk zeroes out-of-volume)
    auto sqsm = [&](float4 a0, float4 a1, float4 a2, float4 a3, int4 t,
                    float mk) -> float4 {
        float4 o;
        #define DO(K)                                                          \
        {                                                                      \
            float m = fmaxf(fmaxf(a0.K, a1.K), fmaxf(a2.K, a3.K));             \
            float e0 = expf(a0.K - m), e1 = expf(a1.K - m);                    \
            float e2 = expf(a2.K - m), e3 = expf(a3.K - m);                    \
            float inv = 1.0f / (e0 + e1 + e2 + e3);                            \
            float ec = (cc == 0) ? e0 : (cc == 1) ? e1 : (cc == 2) ? e2 : e3;  \
            float d = ec * inv - ((t.K == cc) ? 1.0f : 0.0f);                  \
            o.K = d * d * mk;                                                  \
        }
        DO(x) DO(y) DO(z) DO(w)
        #undef DO
        return o;
    };

    auto commit = [&](int L) {
        float4* sl = lin + SLOT(L) * IN_P4;
        float4 v0;
        if (PASS1) v0 = sqsm(pA0, pA1, pA2, pA3, pT0, pm0);
        else       v0 = pf0;
        i_m = i_c; i_c = i_p; i_p = v0;          // shift input chain
        sl[tid + 64] = v0;                       // input row trow+2
        if (act1) {
            float4 v1;
            if (PASS1) v1 = sqsm(pB0, pB1, pB2, pB3, pT1, pm1);
            else       v1 = pf1;
            sl[loff1] = v1;
        }
    };

    auto s1_phase = [&](int z) {
        const float zokf = ((unsigned)z < 128u) ? 1.f : 0.f;
        const float4* pzm = lin + SLOT(z - 1) * IN_P4;
        const float4* pzc = lin + SLOT(z)     * IN_P4;
        const float4* pzp = lin + SLOT(z + 1) * IN_P4;
        float4* o = ls1 + SLOT(z) * S1_P4;
        // primary: s1 row trow+1; center/z-neighbors from registers
        {
            float4 qU = pzc[tid + 32];
            float4 qD = pzc[tid + 96];
            float4 qL = pzc[tid + 63];
            float4 qR = pzc[tid + 65];
            float lf = qL.w * lmask;
            float rt = qR.x * rmask;
            float4 v;
            v.x = fmaxf((i_c.x + lf    + i_c.y + qU.x + qD.x + i_m.x + i_p.x) * wk + bs, 0.f) * zokf;
            v.y = fmaxf((i_c.y + i_c.x + i_c.z + qU.y + qD.y + i_m.y + i_p.y) * wk + bs, 0.f) * zokf;
            v.z = fmaxf((i_c.z + i_c.y + i_c.w + qU.z + qD.z + i_m.z + i_p.z) * wk + bs, 0.f) * zokf;
            v.w = fmaxf((i_c.w + i_c.z + rt    + qU.w + qD.w + i_m.w + i_p.w) * wk + bs, 0.f) * zokf;
            s_m = s_c; s_c = s_p; s_p = v;       // shift s1 chain
            o[tid + 32] = v;
        }
        // ragged s1 rows 0,9: all-LDS path
        if (sact1) {
            float4 qC = pzc[ci1];
            float4 qL = pzc[ci1 - 1];
            float4 qR = pzc[ci1 + 1];
            float4 qU = pzc[ci1 - 32];
            float4 qD = pzc[ci1 + 32];
            float4 qm = pzm[ci1];
            float4 qp = pzp[ci1];
            float lf = qL.w * lmask;
            float rt = qR.x * rmask;
            float mk = zokf * m1;
            float4 v;
            v.x = fmaxf((qC.x + lf   + qC.y + qU.x + qD.x + qm.x + qp.x) * wk + bs, 0.f) * mk;
            v.y = fmaxf((qC.y + qC.x + qC.z + qU.y + qD.y + qm.y + qp.y) * wk + bs, 0.f) * mk;
            v.z = fmaxf((qC.z + qC.y + qC.w + qU.z + qD.z + qm.z + qp.z) * wk + bs, 0.f) * mk;
            v.w = fmaxf((qC.w + qC.z + rt   + qU.w + qD.w + qm.w + qp.w) * wk + bs, 0.f) * mk;
            o[so1] = v;
        }
    };

    double part = 0.0;

    // ---- prologue ----
    prefetch(zb - 2); commit(zb - 2);
    prefetch(zb - 1); commit(zb - 1);
    prefetch(zb);     commit(zb);
    prefetch(zb + 1);                      // stays in regs until next commit
    __syncthreads();
    s1_phase(zb - 1);
    __syncthreads();

    // ---- main loop ----
    for (int L = zb + 1; L <= zb + 17; ++L) {
        commit(L);
        if (L <= zb + 16) prefetch(L + 1);
        __syncthreads();
        s1_phase(L - 1);
        __syncthreads();
        const int zo = L - 2;              // owned output plane
        if (zo >= zb) {
            const float4* szc = ls1 + SLOT(zo) * S1_P4;
            float4 u4 = szc[tid];          // s1 row trow
            float4 d4 = szc[tid + 64];     // s1 row trow+2
            float4 l4 = szc[tid + 31];
            float4 r4 = szc[tid + 33];
            float lf = l4.w * lmask;
            float rt = r4.x * rmask;
            float4 v;
            v.x = fmaxf((s_c.x + lf    + s_c.y + u4.x + d4.x + s_m.x + s_p.x) * wk + bs, 0.f);
            v.y = fmaxf((s_c.y + s_c.x + s_c.z + u4.y + d4.y + s_m.y + s_p.y) * wk + bs, 0.f);
            v.z = fmaxf((s_c.z + s_c.y + s_c.w + u4.z + d4.z + s_m.z + s_p.z) * wk + bs, 0.f);
            v.w = fmaxf((s_c.w + s_c.z + rt    + u4.w + d4.w + s_m.w + s_p.w) * wk + bs, 0.f);
            if (store) dp[((size_t)zo << 12) + goff0] = v;
            part += (double)c1 * ((double)s_c.x + (double)s_c.y + (double)s_c.z + (double)s_c.w)
                  + (double)c2 * ((double)v.x   + (double)v.y   + (double)v.z   + (double)v.w);
        }
    }

    // ---- block reduction; slot bid is private to this block ----
    #pragma unroll
    for (int off = 32; off > 0; off >>= 1)
        part += __shfl_down(part, off, 64);
    if ((tid & 63) == 0) wsum[tid >> 6] = part;
    __syncthreads();
    if (tid == 0) {
        double tot = (wsum[0] + wsum[1] + wsum[2] + wsum[3]) * (double)weight[bc];
        if (PASS1) accs[bid] = tot;            // init (ws is poisoned)
        else       atomicAdd(&accs[bid], tot); // contention-free
    }
}

// Reduce the NACC per-block accumulators -> scalar mean.
__global__ __launch_bounds__(1024) void finalize_kernel(
    const double* __restrict__ accs, float* __restrict__ out)
{
    __shared__ double wsum[16];
    double v = accs[threadIdx.x];
    #pragma unroll
    for (int off = 32; off > 0; off >>= 1)
        v += __shfl_down(v, off, 64);
    int lane = threadIdx.x & 63;
    int wid  = threadIdx.x >> 6;
    if (lane == 0) wsum[wid] = v;
    __syncthreads();
    if (threadIdx.x == 0) {
        double tot = 0.0;
        #pragma unroll
        for (int i = 0; i < 16; ++i) tot += wsum[i];
        out[0] = (float)(tot / (double)NTOT);
    }
}

extern "C" void kernel_launch(void* const* d_in, const int* in_sizes, int n_in,
                              void* d_out, int out_size, void* d_ws, size_t ws_size,
                              hipStream_t stream) {
    const float4* in4    = (const float4*)d_in[0];
    const int4*   tg4    = (const int4*)d_in[1];
    const float*  weight = (const float*)d_in[2];
    const float*  kern   = (const float*)d_in[3];
    const float*  bias   = (const float*)d_in[4];
    float* out = (float*)d_out;

    char* ws = (char*)d_ws;
    float4* buf0 = (float4*)ws;
    float4* buf1 = (float4*)(ws + (size_t)NTOT * sizeof(float));
    double* accs = (double*)(ws + (size_t)NTOT * 2 * sizeof(float));

    // pass 1: fused softmax+sq + erosion steps 1,2 (writes accs slots directly)
    erode2_kernel<1><<<1024, 256, 0, stream>>>(
        buf1, in4, tg4, buf0, kern, bias, weight, 1.f, 4.f, 1, accs);
    // passes 2..5: erosion steps 3..10; last pass skips the store
    erode2_kernel<0><<<1024, 256, 0, stream>>>(
        buf0, in4, tg4, buf1, kern, bias, weight, 9.f, 16.f, 1, accs);
    erode2_kernel<0><<<1024, 256, 0, stream>>>(
        buf1, in4, tg4, buf0, kern, bias, weight, 25.f, 36.f, 1, accs);
    erode2_kernel<0><<<1024, 256, 0, stream>>>(
        buf0, in4, tg4, buf1, kern, bias, weight, 49.f, 64.f, 1, accs);
    erode2_kernel<0><<<1024, 256, 0, stream>>>(
        buf1, in4, tg4, buf0, kern, bias, weight, 81.f, 100.f, 0, accs);

    finalize_kernel<<<1, 1024, 0, stream>>>(accs, out);
}